// Round 7
// baseline (151.807 us; speedup 1.0000x reference)
//
#include <hip/hip_runtime.h>

// KL(p||q) for diagonal Gaussians, reduced to a single scalar:
// out = (0.5/B) * sum_{b,d} [ (qlv-plv) + exp(plv-qlv) + (pmu-qmu)^2*exp(-qlv) - 1 ]
//
// Two-stage reduction. History: four structurally different stage-1 kernels
// (grid-stride, SW-pipeline, 16-upfront NT scattered, 16-upfront NT
// contiguous) all land 37-47us (~3.6 TB/s delivered read) -> per-CU read
// path (outstanding-line/MSHR x latency) is the suspected cap, not MLP.
// This version adds an XCD-contiguity swizzle: dispatch is round-robin over
// 8 XCDs (blk & 7), so remap block -> window such that each XCD reads one
// contiguous 1/8 span of each array. Shorter-latency L2/L3 service raises
// the Little's-law BW at fixed outstanding-line count.

typedef float vf4 __attribute__((ext_vector_type(4)));

__device__ __forceinline__ float kl4(const vf4 a, const vf4 b,
                                     const vf4 c, const vf4 d) {
  float acc = 0.0f, lr, dx;
  #pragma unroll
  for (int k = 0; k < 4; ++k) {
    lr = d[k] - b[k];
    dx = a[k] - c[k];
    acc += lr + __expf(-lr) + dx * dx * __expf(-d[k]) - 1.0f;
  }
  return acc;
}

__device__ __forceinline__ float block_reduce_256(float acc) {
  #pragma unroll
  for (int off = 32; off > 0; off >>= 1)
    acc += __shfl_down(acc, off, 64);
  __shared__ float sm[4];
  const int lane = threadIdx.x & 63;
  const int wid  = threadIdx.x >> 6;
  if (lane == 0) sm[wid] = acc;
  __syncthreads();
  return sm[0] + sm[1] + sm[2] + sm[3];
}

// Stage 1: 2048 blocks x 256 threads. Swizzled window id: XCD x (= blk&7)
// gets windows [x*256, (x+1)*256) -> one contiguous 16.8MB span per array
// per XCD. Within a window: 1024 vf4 = 16KB contiguous; thread reads 4 tiers
// at +256 vf4. All 16 loads issued before any compute (nontemporal).
__global__ __launch_bounds__(256) void kl_partial_kernel(
    const vf4* __restrict__ pmu,
    const vf4* __restrict__ plv,
    const vf4* __restrict__ qmu,
    const vf4* __restrict__ qlv,
    float* __restrict__ partials) {
  const int blk = blockIdx.x;
  const int win = (blk & 7) * 256 + (blk >> 3);   // XCD-contiguous remap
  const int base = win * 1024 + threadIdx.x;

  vf4 A[4], Bv[4], C[4], Dv[4];
  #pragma unroll
  for (int t = 0; t < 4; ++t) {
    const int i = base + t * 256;
    A[t]  = __builtin_nontemporal_load(&pmu[i]);
    Bv[t] = __builtin_nontemporal_load(&plv[i]);
    C[t]  = __builtin_nontemporal_load(&qmu[i]);
    Dv[t] = __builtin_nontemporal_load(&qlv[i]);
  }

  float acc = 0.0f;
  #pragma unroll
  for (int t = 0; t < 4; ++t)
    acc += kl4(A[t], Bv[t], C[t], Dv[t]);

  const float blocksum = block_reduce_256(acc);
  if (threadIdx.x == 0) partials[blk] = blocksum;
}

// Stage 2: single block folds nparts partials, scales, writes the scalar.
__global__ __launch_bounds__(256) void kl_final_kernel(
    const float* __restrict__ partials, float* __restrict__ out,
    int nparts, float scale) {
  float acc = 0.0f;
  for (int i = threadIdx.x; i < nparts; i += 256) acc += partials[i];
  const float total = block_reduce_256(acc);
  if (threadIdx.x == 0) out[0] = total * scale;
}

extern "C" void kernel_launch(void* const* d_in, const int* in_sizes, int n_in,
                              void* d_out, int out_size, void* d_ws, size_t ws_size,
                              hipStream_t stream) {
  const vf4* pmu = (const vf4*)d_in[0];
  const vf4* plv = (const vf4*)d_in[1];
  const vf4* qmu = (const vf4*)d_in[2];
  const vf4* qlv = (const vf4*)d_in[3];
  float* out = (float*)d_out;
  float* partials = (float*)d_ws;       // 2048 floats = 8 KB scratch

  const int B = 16384;
  const float scale = 0.5f / (float)B;

  const int block = 256;
  const int grid = 2048;                // 2048 windows x 1024 vf4 = 2M vf4/array
  kl_partial_kernel<<<grid, block, 0, stream>>>(pmu, plv, qmu, qlv, partials);
  kl_final_kernel<<<1, block, 0, stream>>>(partials, out, grid, scale);
}

// Round 8
// 149.218 us; speedup vs baseline: 1.0174x; 1.0174x over previous
//
#include <hip/hip_runtime.h>

// KL(p||q) for diagonal Gaussians, reduced to a single scalar:
// out = (0.5/B) * sum_{b,d} [ (qlv-plv) + exp(plv-qlv) + (pmu-qmu)^2*exp(-qlv) - 1 ]
//
// Stage 1 now stages via __builtin_amdgcn_global_load_lds (width=16): loads
// DMA straight to LDS with no VGPR writeback, removing register-return
// serialization (the suspected ~3.8 TB/s cap; register versions plateaued
// 35-46us). Each block: contiguous 8KB window per array -> 32KB LDS,
// ~5 blocks/CU so other blocks compute while one drains its barrier.
// XCD swizzle from round 7 REVERTED (regressed 142.7 -> 151.8).

typedef float vf4 __attribute__((ext_vector_type(4)));

__device__ __forceinline__ float kl4(const vf4 a, const vf4 b,
                                     const vf4 c, const vf4 d) {
  float acc = 0.0f, lr, dx;
  #pragma unroll
  for (int k = 0; k < 4; ++k) {
    lr = d[k] - b[k];
    dx = a[k] - c[k];
    acc += lr + __expf(-lr) + dx * dx * __expf(-d[k]) - 1.0f;
  }
  return acc;
}

__device__ __forceinline__ float block_reduce_256(float acc) {
  #pragma unroll
  for (int off = 32; off > 0; off >>= 1)
    acc += __shfl_down(acc, off, 64);
  __shared__ float sm[4];
  const int lane = threadIdx.x & 63;
  const int wid  = threadIdx.x >> 6;
  if (lane == 0) sm[wid] = acc;
  __syncthreads();
  return sm[0] + sm[1] + sm[2] + sm[3];
}

__device__ __forceinline__ void load_to_lds16(const vf4* g, vf4* l) {
  // gptr per-lane; LDS dest = wave-uniform base + lane*16 (HW rule).
  __builtin_amdgcn_global_load_lds(
      (const __attribute__((address_space(1))) void*)g,
      (__attribute__((address_space(3))) void*)l, 16, 0, 0);
}

// Stage 1: 4096 blocks x 256 threads. Block owns vf4 range
// [blk*512, blk*512+512) in each array (8KB contiguous window per array).
// LDS layout: arr*512 + offset (vf4 units), 32KB total.
__global__ __launch_bounds__(256) void kl_partial_kernel(
    const vf4* __restrict__ pmu,
    const vf4* __restrict__ plv,
    const vf4* __restrict__ qmu,
    const vf4* __restrict__ qlv,
    float* __restrict__ partials) {
  __shared__ vf4 lds[4 * 512];   // 32 KB

  const int tid  = threadIdx.x;
  const int lane = tid & 63;
  const int w    = tid >> 6;           // wave id 0..3
  const int gbase = blockIdx.x * 512;  // window start (vf4 units)

  const vf4* arrs[4] = {pmu, plv, qmu, qlv};
  // Each wave stages 2 x 1KB lines per array: 8 global_load_lds per wave,
  // all in flight simultaneously, zero VGPR returns.
  #pragma unroll
  for (int arr = 0; arr < 4; ++arr) {
    #pragma unroll
    for (int t = 0; t < 2; ++t) {
      const int off = w * 128 + t * 64;        // vf4 offset inside window
      load_to_lds16(&arrs[arr][gbase + off + lane], &lds[arr * 512 + off]);
    }
  }
  __syncthreads();   // compiler emits s_waitcnt vmcnt(0) before s_barrier

  float acc = 0.0f;
  #pragma unroll
  for (int k = 0; k < 2; ++k) {
    const int idx = tid + k * 256;
    acc += kl4(lds[0 * 512 + idx], lds[1 * 512 + idx],
               lds[2 * 512 + idx], lds[3 * 512 + idx]);
  }

  const float blocksum = block_reduce_256(acc);
  if (tid == 0) partials[blockIdx.x] = blocksum;
}

// Stage 2: single block folds nparts partials, scales, writes the scalar.
__global__ __launch_bounds__(256) void kl_final_kernel(
    const float* __restrict__ partials, float* __restrict__ out,
    int nparts, float scale) {
  float acc = 0.0f;
  for (int i = threadIdx.x; i < nparts; i += 256) acc += partials[i];
  const float total = block_reduce_256(acc);
  if (threadIdx.x == 0) out[0] = total * scale;
}

extern "C" void kernel_launch(void* const* d_in, const int* in_sizes, int n_in,
                              void* d_out, int out_size, void* d_ws, size_t ws_size,
                              hipStream_t stream) {
  const vf4* pmu = (const vf4*)d_in[0];
  const vf4* plv = (const vf4*)d_in[1];
  const vf4* qmu = (const vf4*)d_in[2];
  const vf4* qlv = (const vf4*)d_in[3];
  float* out = (float*)d_out;
  float* partials = (float*)d_ws;       // 4096 floats = 16 KB scratch

  const int B = 16384;
  const float scale = 0.5f / (float)B;

  const int block = 256;
  const int grid = 4096;                // 4096 x 512 vf4 = 2M vf4 per array
  kl_partial_kernel<<<grid, block, 0, stream>>>(pmu, plv, qmu, qlv, partials);
  kl_final_kernel<<<1, block, 0, stream>>>(partials, out, grid, scale);
}